// Round 1
// baseline (4894.482 us; speedup 1.0000x reference)
//
#include <hip/hip_runtime.h>
#include <hip/hip_fp16.h>

// ---------------------------------------------------------------------------
// BiLSTM  B=32 T=2048 D=512 H=256  (4H = 1024 gates per direction)
// Phases: flags -> lengths -> weight repack (fp16) -> input GEMM (MFMA f16)
//         -> persistent recurrent kernel (64 WGs, weights resident LDS+VGPR)
// ---------------------------------------------------------------------------

typedef _Float16 f16;
typedef _Float16 f16x2 __attribute__((ext_vector_type(2)));
typedef _Float16 f16x4 __attribute__((ext_vector_type(4)));
typedef _Float16 f16x8 __attribute__((ext_vector_type(8)));
typedef float    f32x4 __attribute__((ext_vector_type(4)));

#define NB   32
#define NT   2048
#define ND   512
#define NH   256
#define NG   1024      // 4*H per direction
#define MTOT 65536     // NB*NT

// ---- workspace layout (bytes) ----
#define OFF_PRE   0UL                                   // fp16 [65536][2048]
#define SZ_PRE    (65536UL * 2048UL * 2UL)              // 256 MiB
#define OFF_WALL  (OFF_PRE + SZ_PRE)                    // fp16 [2048][512]
#define SZ_WALL   (2048UL * 512UL * 2UL)
#define OFF_WP    (OFF_WALL + SZ_WALL)                  // f16x2 [2][192][512]
#define SZ_WP     (2UL * 192UL * 512UL * 4UL)
#define OFF_WLDS  (OFF_WP + SZ_WP)                      // uint2 [2][16384]
#define SZ_WLDS   (2UL * 16384UL * 8UL)
#define OFF_BSUM  (OFF_WLDS + SZ_WLDS)                  // float [2][1024]
#define SZ_BSUM   (2048UL * 4UL)
#define OFF_FLAGS (OFF_BSUM + SZ_BSUM)                  // int [65536]
#define SZ_FLAGS  (65536UL * 4UL)
#define OFF_LEN   (OFF_FLAGS + SZ_FLAGS)                // int [32]
#define SZ_LEN    (128UL)
#define OFF_Z     (OFF_LEN + SZ_LEN)                    // 16B of zeros
#define SZ_Z      (16UL)

#if __has_builtin(__builtin_amdgcn_fdot2)
#define FDOT2(a, b, c) __builtin_amdgcn_fdot2((a), (b), (c), false)
#else
#define FDOT2(a, b, c) ((c) + (float)(a)[0] * (float)(b)[0] + (float)(a)[1] * (float)(b)[1])
#endif

__device__ __forceinline__ float sigm_f(float x) {
    float t = __expf(-fabsf(x));
    float s = 1.0f / (1.0f + t);
    return x >= 0.0f ? s : 1.0f - s;
}
__device__ __forceinline__ float tanh_f(float x) {
    float t = __expf(-2.0f * fabsf(x));     // in (0,1], never overflows
    float r = (1.0f - t) / (1.0f + t);
    return x >= 0.0f ? r : -r;
}

// ---------------------------------------------------------------------------
// per-(b,t) nonzero flag
__global__ void k_flags(const float* __restrict__ x, int* __restrict__ flags) {
    int bt = blockIdx.x;                      // 65536 blocks
    int i  = threadIdx.x;                     // 256 threads
    float2 v = ((const float2*)(x + (size_t)bt * ND))[i];
    int nz = (v.x != 0.0f) || (v.y != 0.0f);
    unsigned long long m = __ballot(nz);
    __shared__ int sf[4];
    if ((i & 63) == 0) sf[i >> 6] = (m != 0ULL);
    __syncthreads();
    if (i == 0) flags[bt] = sf[0] | sf[1] | sf[2] | sf[3];
}

// lengths[b] = sum_t flags[b][t]
__global__ void k_lenred(const int* __restrict__ flags, int* __restrict__ lengths) {
    int b = blockIdx.x, i = threadIdx.x;      // 32 x 256
    int s = 0;
#pragma unroll
    for (int k = 0; k < 8; ++k) s += flags[b * NT + i + k * 256];
    for (int o = 32; o > 0; o >>= 1) s += __shfl_down(s, o);
    __shared__ int sp[4];
    if ((i & 63) == 0) sp[i >> 6] = s;
    __syncthreads();
    if (i == 0) lengths[b] = sp[0] + sp[1] + sp[2] + sp[3];
}

// stack Wf_ih / Wb_ih into fp16 Wall[2048][512]
__global__ void k_wall(const float* __restrict__ Wf, const float* __restrict__ Wb,
                       f16* __restrict__ wall) {
    int idx = blockIdx.x * 256 + threadIdx.x; // 1024 blocks -> 262144 threads, 4 elems each
    int e4 = idx * 4;
    int n = e4 >> 9, k = e4 & 511;
    const float* src = (n < 1024 ? Wf + (size_t)n * 512 : Wb + (size_t)(n - 1024) * 512) + k;
    float4 v = *(const float4*)src;
    f16x4 o;
    o[0] = (f16)v.x; o[1] = (f16)v.y; o[2] = (f16)v.z; o[3] = (f16)v.w;
    *(f16x4*)(wall + (size_t)n * 512 + k) = o;
}

// repack Whh into (a) per-thread register stream wp[dir][e][j]  (k < 192)
//                 (b) LDS image wldsg[dir][(cc*2+hf)*1024+row]  (k in [192,256))
//                 (c) bias sums, (d) zero slot
__global__ void k_repack(const float* __restrict__ Wfhh, const float* __restrict__ Wbhh,
                         const float* __restrict__ bfi, const float* __restrict__ bfh,
                         const float* __restrict__ bbi, const float* __restrict__ bbh,
                         f16x2* __restrict__ wp, uint2* __restrict__ wldsg,
                         float* __restrict__ bsum, unsigned int* __restrict__ zslot) {
    int blk = blockIdx.x, tid = threadIdx.x;  // 453 blocks x 512
    if (blk < 384) {
        int dir = blk / 192, e = blk % 192;
        const float* W = dir ? Wbhh : Wfhh;
        int r = e / 96, c = e % 96;           // r: which of the 2 rows, c: k-pair
        int row = tid + r * 512;
        f16x2 v;
        v[0] = (f16)W[row * 256 + 2 * c];
        v[1] = (f16)W[row * 256 + 2 * c + 1];
        wp[((size_t)(dir * 192 + e)) * 512 + tid] = v;
    } else if (blk < 448) {
        int idx = (blk - 384) * 512 + tid;    // 32768 elems
        int dir = idx >> 14, rem = idx & 16383;
        int top = rem >> 10, row = rem & 1023;
        int kb = 192 + (top >> 1) * 8 + (top & 1) * 4;
        const float* W = dir ? Wbhh : Wfhh;
        f16x2 lo, hi;
        lo[0] = (f16)W[row * 256 + kb + 0]; lo[1] = (f16)W[row * 256 + kb + 1];
        hi[0] = (f16)W[row * 256 + kb + 2]; hi[1] = (f16)W[row * 256 + kb + 3];
        uint2 u;
        u.x = __builtin_bit_cast(unsigned int, lo);
        u.y = __builtin_bit_cast(unsigned int, hi);
        wldsg[(size_t)dir * 16384 + rem] = u;
    } else if (blk < 452) {
        int idx = (blk - 448) * 512 + tid;    // 2048
        int dir = idx >> 10, g = idx & 1023;
        bsum[idx] = dir ? (bbi[g] + bbh[g]) : (bfi[g] + bfh[g]);
    } else {
        if (tid < 4) zslot[tid] = 0u;
    }
}

// ---------------------------------------------------------------------------
// Pre[m][n] = x[m][:] @ Wall[n][:]   (fp16 out, fp32 acc)  M=65536 N=2048 K=512
// 128x128 tile, BK=32, 8 waves (each 64x32), double-buffered LDS, reg-staged.
__launch_bounds__(512, 2)
__global__ void k_gemm(const float* __restrict__ X, const f16* __restrict__ Wall,
                       f16* __restrict__ Pre) {
    __shared__ f16 Al[2][128 * 32];
    __shared__ f16 Bl[2][128 * 32];
    int bid = blockIdx.x;
    int mblk = bid >> 4, nblk = bid & 15;     // n-fastest: A panel shared in L2
    int m0 = mblk * 128, n0 = nblk * 128;
    int tid = threadIdx.x;
    int lane = tid & 63, w = tid >> 6;
    int wm = w >> 2, wn = w & 3;              // wave quadrant: 64m x 32n
    int sr = tid >> 2, skq = tid & 3;         // A staging: row, 8-float quarter
    const float* xsrc = X + (size_t)(m0 + sr) * ND + skq * 8;
    const f16*  bsrc = Wall + (size_t)(n0 + (tid >> 2)) * ND + (tid & 3) * 8;

    f32x4 acc[4][2];
#pragma unroll
    for (int a = 0; a < 4; ++a)
#pragma unroll
        for (int b = 0; b < 2; ++b) acc[a][b] = (f32x4){0.f, 0.f, 0.f, 0.f};

    // prologue: stage k-step 0 into buf 0
    {
        float4 v0 = *(const float4*)(xsrc);
        float4 v1 = *(const float4*)(xsrc + 4);
        f16x8 bv = *(const f16x8*)(bsrc);
        f16x8 h8;
        h8[0] = (f16)v0.x; h8[1] = (f16)v0.y; h8[2] = (f16)v0.z; h8[3] = (f16)v0.w;
        h8[4] = (f16)v1.x; h8[5] = (f16)v1.y; h8[6] = (f16)v1.z; h8[7] = (f16)v1.w;
        *(f16x8*)&Al[0][sr * 32 + skq * 8] = h8;
        *(f16x8*)&Bl[0][tid * 8] = bv;
        __syncthreads();
    }

    for (int kk = 0; kk < 16; ++kk) {
        int buf = kk & 1;
        float4 v0, v1; f16x8 bv;
        bool more = (kk < 15);
        if (more) {
            v0 = *(const float4*)(xsrc + (kk + 1) * 32);
            v1 = *(const float4*)(xsrc + (kk + 1) * 32 + 4);
            bv = *(const f16x8*)(bsrc + (kk + 1) * 32);
        }
        f16x8 af[4], bf[2];
#pragma unroll
        for (int mt = 0; mt < 4; ++mt)
            af[mt] = *(const f16x8*)&Al[buf][(wm * 64 + mt * 16 + (lane & 15)) * 32 + (lane >> 4) * 8];
#pragma unroll
        for (int nt = 0; nt < 2; ++nt)
            bf[nt] = *(const f16x8*)&Bl[buf][(wn * 32 + nt * 16 + (lane & 15)) * 32 + (lane >> 4) * 8];
#pragma unroll
        for (int mt = 0; mt < 4; ++mt)
#pragma unroll
            for (int nt = 0; nt < 2; ++nt)
                acc[mt][nt] = __builtin_amdgcn_mfma_f32_16x16x32_f16(af[mt], bf[nt], acc[mt][nt], 0, 0, 0);
        if (more) {
            f16x8 h8;
            h8[0] = (f16)v0.x; h8[1] = (f16)v0.y; h8[2] = (f16)v0.z; h8[3] = (f16)v0.w;
            h8[4] = (f16)v1.x; h8[5] = (f16)v1.y; h8[6] = (f16)v1.z; h8[7] = (f16)v1.w;
            *(f16x8*)&Al[buf ^ 1][sr * 32 + skq * 8] = h8;
            *(f16x8*)&Bl[buf ^ 1][tid * 8] = bv;
        }
        __syncthreads();
    }

    int col = lane & 15, rg = lane >> 4;
#pragma unroll
    for (int mt = 0; mt < 4; ++mt)
#pragma unroll
        for (int nt = 0; nt < 2; ++nt)
#pragma unroll
            for (int q = 0; q < 4; ++q) {
                int m = m0 + wm * 64 + mt * 16 + rg * 4 + q;
                int n = n0 + wn * 32 + nt * 16 + col;
                Pre[(size_t)m * 2048 + n] = (f16)acc[mt][nt][q];
            }
}

// ---------------------------------------------------------------------------
// Persistent recurrent kernel: 64 WGs, one (batch, dir) each, 512 threads.
// Thread j owns gate rows j and j+512. Whh fp16: k<192 in 192 VGPRs/thread,
// k in [192,256) in 128 KiB LDS. h broadcast via LDS (fp16).
__launch_bounds__(512, 2)
__global__ void k_recur(const f16* __restrict__ Pre, const f16x2* __restrict__ wp,
                        const uint2* __restrict__ wldsg, const float* __restrict__ bsum,
                        const int* __restrict__ lengths, const f16* __restrict__ zslot,
                        float* __restrict__ out) {
    extern __shared__ char smem[];            // [0,131072) wlds | h (512B) | a_exch (1KB)
    f16*   hbuf = (f16*)(smem + 131072);
    float* aex  = (float*)(smem + 131072 + 512);

    int bid = blockIdx.x;
    int b = bid >> 1, dir = bid & 1;
    int j = threadIdx.x;
    int L = lengths[b];

    // stage LDS weight image (128 KiB), coalesced
    {
        const char* src = (const char*)(wldsg + (size_t)dir * 16384);
#pragma unroll
        for (int s = 0; s < 16; ++s) {
            int q = s * 512 + j;
            *(uint4*)(smem + (size_t)q * 16) = *(const uint4*)(src + (size_t)q * 16);
        }
    }
    // load register weights: wreg[e], e = row_half*96 + k_pair  (k<192)
    f16x2 wreg[192];
    {
        const f16x2* wpp = wp + (size_t)(dir * 192) * 512 + j;
#pragma unroll
        for (int e = 0; e < 192; ++e) wreg[e] = wpp[(size_t)e * 512];
    }
    float bs0 = bsum[dir * 1024 + j];
    float bs1 = bsum[dir * 1024 + j + 512];
    if (j < 32) *(uint4*)(hbuf + j * 8) = (uint4){0u, 0u, 0u, 0u};
    __syncthreads();

    float cst = 0.0f;
    const size_t baseRow = (size_t)b * NT;

    // prefetch pre-activations for t=0
    f16 pn0, pn1;
    {
        int rt = dir ? (L - 1) : 0;
        const f16* q0 = Pre + (baseRow + rt) * 2048 + dir * 1024 + j;
        pn0 = q0[0]; pn1 = q0[512];
    }

    for (int t = 0; t < NT; ++t) {
        float pre0 = (float)pn0, pre1 = (float)pn1;
        // issue prefetch for t+1 (latency hidden under the dot phase)
        {
            int tn = t + 1;
            int rt = dir ? (L - 1 - tn) : tn;
            const f16 *q0, *q1;
            if (tn < NT && rt >= 0) {
                q0 = Pre + (baseRow + rt) * 2048 + dir * 1024 + j;
                q1 = q0 + 512;
            } else {
                q0 = zslot; q1 = zslot;
            }
            pn0 = *q0; pn1 = *q1;
        }

        float a0 = bs0 + pre0, a1 = 0.0f;     // row0 accumulators (split for ILP)
        float b0 = bs1 + pre1, b1 = 0.0f;     // row1 accumulators
#pragma unroll
        for (int c = 0; c < 32; ++c) {
            f16x8 hv = *(const f16x8*)(hbuf + c * 8);   // broadcast read
            f16x2 h2q[4];
            h2q[0][0] = hv[0]; h2q[0][1] = hv[1];
            h2q[1][0] = hv[2]; h2q[1][1] = hv[3];
            h2q[2][0] = hv[4]; h2q[2][1] = hv[5];
            h2q[3][0] = hv[6]; h2q[3][1] = hv[7];
            f16x2 w0q[4], w1q[4];
            if (c < 24) {
                w0q[0] = wreg[c * 4 + 0]; w0q[1] = wreg[c * 4 + 1];
                w0q[2] = wreg[c * 4 + 2]; w0q[3] = wreg[c * 4 + 3];
                w1q[0] = wreg[96 + c * 4 + 0]; w1q[1] = wreg[96 + c * 4 + 1];
                w1q[2] = wreg[96 + c * 4 + 2]; w1q[3] = wreg[96 + c * 4 + 3];
            } else {
                int cc = c - 24;
                uint2 u00 = *(const uint2*)(smem + ((size_t)(cc * 2 + 0) * 1024 + j) * 8);
                uint2 u01 = *(const uint2*)(smem + ((size_t)(cc * 2 + 1) * 1024 + j) * 8);
                uint2 u10 = *(const uint2*)(smem + ((size_t)(cc * 2 + 0) * 1024 + j + 512) * 8);
                uint2 u11 = *(const uint2*)(smem + ((size_t)(cc * 2 + 1) * 1024 + j + 512) * 8);
                w0q[0] = __builtin_bit_cast(f16x2, u00.x); w0q[1] = __builtin_bit_cast(f16x2, u00.y);
                w0q[2] = __builtin_bit_cast(f16x2, u01.x); w0q[3] = __builtin_bit_cast(f16x2, u01.y);
                w1q[0] = __builtin_bit_cast(f16x2, u10.x); w1q[1] = __builtin_bit_cast(f16x2, u10.y);
                w1q[2] = __builtin_bit_cast(f16x2, u11.x); w1q[3] = __builtin_bit_cast(f16x2, u11.y);
            }
            a0 = FDOT2(h2q[0], w0q[0], a0);
            b0 = FDOT2(h2q[0], w1q[0], b0);
            a1 = FDOT2(h2q[1], w0q[1], a1);
            b1 = FDOT2(h2q[1], w1q[1], b1);
            a0 = FDOT2(h2q[2], w0q[2], a0);
            b0 = FDOT2(h2q[2], w1q[2], b0);
            a1 = FDOT2(h2q[3], w0q[3], a1);
            b1 = FDOT2(h2q[3], w1q[3], b1);
        }
        float z0 = a0 + a1;                   // j<256: i-gate | j>=256: f-gate
        float z1 = b0 + b1;                   // j<256: g-gate | j>=256: o-gate

        if (j < 256) aex[j] = sigm_f(z0) * tanh_f(z1);   // sigma(i)*tanh(g)
        __syncthreads();
        if (j >= 256) {
            int i = j - 256;
            cst = sigm_f(z0) * cst + aex[i];             // sigma(f)*c + a
            float h = sigm_f(z1) * tanh_f(cst);          // sigma(o)*tanh(c)
            out[(baseRow + t) * 512 + dir * 256 + i] = h;
            hbuf[i] = (f16)h;
        }
        __syncthreads();
    }
}

// ---------------------------------------------------------------------------
extern "C" void kernel_launch(void* const* d_in, const int* in_sizes, int n_in,
                              void* d_out, int out_size, void* d_ws, size_t ws_size,
                              hipStream_t stream) {
    (void)in_sizes; (void)n_in; (void)out_size; (void)ws_size;
    const float* x     = (const float*)d_in[0];
    const float* Wf_ih = (const float*)d_in[1];
    const float* Wf_hh = (const float*)d_in[2];
    const float* bf_ih = (const float*)d_in[3];
    const float* bf_hh = (const float*)d_in[4];
    const float* Wb_ih = (const float*)d_in[5];
    const float* Wb_hh = (const float*)d_in[6];
    const float* bb_ih = (const float*)d_in[7];
    const float* bb_hh = (const float*)d_in[8];
    float* out = (float*)d_out;

    char* ws = (char*)d_ws;
    f16*          Pre    = (f16*)(ws + OFF_PRE);
    f16*          Wall   = (f16*)(ws + OFF_WALL);
    f16x2*        wp     = (f16x2*)(ws + OFF_WP);
    uint2*        wldsg  = (uint2*)(ws + OFF_WLDS);
    float*        bsum   = (float*)(ws + OFF_BSUM);
    int*          flags  = (int*)(ws + OFF_FLAGS);
    int*          lens   = (int*)(ws + OFF_LEN);
    unsigned int* zslot  = (unsigned int*)(ws + OFF_Z);

    // allow 130 KiB dynamic LDS on the recurrent kernel
    static const size_t RECUR_LDS = 131072 + 512 + 1024;
    hipFuncSetAttribute((const void*)k_recur,
                        hipFuncAttributeMaxDynamicSharedMemorySize, (int)RECUR_LDS);

    k_flags <<<MTOT, 256, 0, stream>>>(x, flags);
    k_lenred<<<NB, 256, 0, stream>>>(flags, lens);
    k_wall  <<<1024, 256, 0, stream>>>(Wf_ih, Wb_ih, Wall);
    k_repack<<<453, 512, 0, stream>>>(Wf_hh, Wb_hh, bf_ih, bf_hh, bb_ih, bb_hh,
                                      wp, wldsg, bsum, zslot);
    k_gemm  <<<(MTOT / 128) * (2048 / 128), 512, 0, stream>>>(x, Wall, Pre);
    k_recur <<<NB * 2, 512, RECUR_LDS, stream>>>(Pre, wp, wldsg, bsum, lens,
                                                 (const f16*)zslot, out);
}

// Round 5
// 3938.106 us; speedup vs baseline: 1.2429x; 1.2429x over previous
//
#include <hip/hip_runtime.h>
#include <hip/hip_fp16.h>

// ---------------------------------------------------------------------------
// BiLSTM  B=32 T=2048 D=512 H=256  (4H = 1024 gates per direction)
// flags -> lengths -> weight repack (fp16) -> input GEMM (MFMA f16)
//       -> persistent recurrent kernel (64 WGs, weights resident LDS+VGPR)
//
// R2 changes vs R1 (resubmitted after three infra timeouts):
//  * k_recur __launch_bounds__(512,1): LDS already forces 1 WG/CU; the old
//    (512,2) capped VGPRs at 128 and spilled wreg[192] to scratch (R1: VGPR=128,
//    VALUBusy 12.5%, 4.47 ms). Now budget = 256 VGPR.
//  * LDS weight image repacked to uint4 per (cc,row): 2x ds_read_b128 per
//    c-iter instead of 4x ds_read_b64.
//  * Parity thread mapping: threads (2u,2u+1) own (i,g)/(f,o) of unit u;
//    cross-gate exchange via __shfl_xor (in-wave), hbuf double-buffered ->
//    ONE barrier per step instead of two, no aex LDS round trip.
// ---------------------------------------------------------------------------

typedef _Float16 f16;
typedef _Float16 f16x2 __attribute__((ext_vector_type(2)));
typedef _Float16 f16x4 __attribute__((ext_vector_type(4)));
typedef _Float16 f16x8 __attribute__((ext_vector_type(8)));
typedef float    f32x4 __attribute__((ext_vector_type(4)));

#define NB   32
#define NT   2048
#define ND   512
#define NH   256
#define NG   1024      // 4*H per direction
#define MTOT 65536     // NB*NT

// ---- workspace layout (bytes) ----
#define OFF_PRE   0UL                                   // fp16 [65536][2048]
#define SZ_PRE    (65536UL * 2048UL * 2UL)              // 256 MiB
#define OFF_WALL  (OFF_PRE + SZ_PRE)                    // fp16 [2048][512]
#define SZ_WALL   (2048UL * 512UL * 2UL)
#define OFF_WP    (OFF_WALL + SZ_WALL)                  // f16x2 [2][192][512]
#define SZ_WP    (2UL * 192UL * 512UL * 4UL)
#define OFF_WLDS  (OFF_WP + SZ_WP)                      // uint4 [2][8][1024]
#define SZ_WLDS   (2UL * 8192UL * 16UL)
#define OFF_BSUM  (OFF_WLDS + SZ_WLDS)                  // float [2][1024]
#define SZ_BSUM   (2048UL * 4UL)
#define OFF_FLAGS (OFF_BSUM + SZ_BSUM)                  // int [65536]
#define SZ_FLAGS  (65536UL * 4UL)
#define OFF_LEN   (OFF_FLAGS + SZ_FLAGS)                // int [32]
#define SZ_LEN    (128UL)
#define OFF_Z     (OFF_LEN + SZ_LEN)                    // 16B of zeros
#define SZ_Z      (16UL)

#if __has_builtin(__builtin_amdgcn_fdot2)
#define FDOT2(a, b, c) __builtin_amdgcn_fdot2((a), (b), (c), false)
#else
#define FDOT2(a, b, c) ((c) + (float)(a)[0] * (float)(b)[0] + (float)(a)[1] * (float)(b)[1])
#endif

__device__ __forceinline__ float sigm_f(float x) {
    float t = __expf(-fabsf(x));
    float s = 1.0f / (1.0f + t);
    return x >= 0.0f ? s : 1.0f - s;
}
__device__ __forceinline__ float tanh_f(float x) {
    float t = __expf(-2.0f * fabsf(x));     // in (0,1], never overflows
    float r = (1.0f - t) / (1.0f + t);
    return x >= 0.0f ? r : -r;
}

// ---------------------------------------------------------------------------
// per-(b,t) nonzero flag
__global__ void k_flags(const float* __restrict__ x, int* __restrict__ flags) {
    int bt = blockIdx.x;                      // 65536 blocks
    int i  = threadIdx.x;                     // 256 threads
    float2 v = ((const float2*)(x + (size_t)bt * ND))[i];
    int nz = (v.x != 0.0f) || (v.y != 0.0f);
    unsigned long long m = __ballot(nz);
    __shared__ int sf[4];
    if ((i & 63) == 0) sf[i >> 6] = (m != 0ULL);
    __syncthreads();
    if (i == 0) flags[bt] = sf[0] | sf[1] | sf[2] | sf[3];
}

// lengths[b] = sum_t flags[b][t]
__global__ void k_lenred(const int* __restrict__ flags, int* __restrict__ lengths) {
    int b = blockIdx.x, i = threadIdx.x;      // 32 x 256
    int s = 0;
#pragma unroll
    for (int k = 0; k < 8; ++k) s += flags[b * NT + i + k * 256];
    for (int o = 32; o > 0; o >>= 1) s += __shfl_down(s, o);
    __shared__ int sp[4];
    if ((i & 63) == 0) sp[i >> 6] = s;
    __syncthreads();
    if (i == 0) lengths[b] = sp[0] + sp[1] + sp[2] + sp[3];
}

// stack Wf_ih / Wb_ih into fp16 Wall[2048][512]
__global__ void k_wall(const float* __restrict__ Wf, const float* __restrict__ Wb,
                       f16* __restrict__ wall) {
    int idx = blockIdx.x * 256 + threadIdx.x; // 1024 blocks
    int e4 = idx * 4;
    int n = e4 >> 9, k = e4 & 511;
    const float* src = (n < 1024 ? Wf + (size_t)n * 512 : Wb + (size_t)(n - 1024) * 512) + k;
    float4 v = *(const float4*)src;
    f16x4 o;
    o[0] = (f16)v.x; o[1] = (f16)v.y; o[2] = (f16)v.z; o[3] = (f16)v.w;
    *(f16x4*)(wall + (size_t)n * 512 + k) = o;
}

// gate-row owned by thread tid slot r (parity mapping):
//   u = tid>>1, p = tid&1; rowA = p ? 256+u : u; row = rowA + r*512
__device__ __forceinline__ int gate_row(int tid, int r) {
    int u = tid >> 1, p = tid & 1;
    return (p ? 256 + u : u) + r * 512;
}

// repack Whh: (a) register stream wp[dir][e][tid], e = r*96 + k_pair (k<192)
//             (b) LDS uint4 image [dir][cc][row] (k in [192,256), 8 k per uint4)
//             (c) bias sums, (d) zero slot
__global__ void k_repack(const float* __restrict__ Wfhh, const float* __restrict__ Wbhh,
                         const float* __restrict__ bfi, const float* __restrict__ bfh,
                         const float* __restrict__ bbi, const float* __restrict__ bbh,
                         f16x2* __restrict__ wp, uint4* __restrict__ wldsg,
                         float* __restrict__ bsum, unsigned int* __restrict__ zslot) {
    int blk = blockIdx.x, tid = threadIdx.x;  // 421 blocks x 512
    if (blk < 384) {
        int dir = blk / 192, e = blk % 192;
        const float* W = dir ? Wbhh : Wfhh;
        int r = e / 96, c = e % 96;           // r: row slot, c: k-pair
        int row = gate_row(tid, r);
        f16x2 v;
        v[0] = (f16)W[row * 256 + 2 * c];
        v[1] = (f16)W[row * 256 + 2 * c + 1];
        wp[((size_t)(dir * 192 + e)) * 512 + tid] = v;
    } else if (blk < 416) {
        int idx = (blk - 384) * 512 + tid;    // 16384 uint4s
        int dir = idx >> 13, rem = idx & 8191;
        int cc = rem >> 10, row = rem & 1023;
        int kb = 192 + cc * 8;
        const float* W = dir ? Wbhh : Wfhh;
        f16x2 p0, p1, p2, p3;
        p0[0] = (f16)W[row * 256 + kb + 0]; p0[1] = (f16)W[row * 256 + kb + 1];
        p1[0] = (f16)W[row * 256 + kb + 2]; p1[1] = (f16)W[row * 256 + kb + 3];
        p2[0] = (f16)W[row * 256 + kb + 4]; p2[1] = (f16)W[row * 256 + kb + 5];
        p3[0] = (f16)W[row * 256 + kb + 6]; p3[1] = (f16)W[row * 256 + kb + 7];
        uint4 u;
        u.x = __builtin_bit_cast(unsigned int, p0);
        u.y = __builtin_bit_cast(unsigned int, p1);
        u.z = __builtin_bit_cast(unsigned int, p2);
        u.w = __builtin_bit_cast(unsigned int, p3);
        wldsg[(size_t)dir * 8192 + rem] = u;
    } else if (blk < 420) {
        int idx = (blk - 416) * 512 + tid;    // 2048
        int dir = idx >> 10, g = idx & 1023;
        bsum[idx] = dir ? (bbi[g] + bbh[g]) : (bfi[g] + bfh[g]);
    } else {
        if (tid < 4) zslot[tid] = 0u;
    }
}

// ---------------------------------------------------------------------------
// Pre[m][n] = x[m][:] @ Wall[n][:]   (fp16 out, fp32 acc)  M=65536 N=2048 K=512
// 128x128 tile, BK=32, 8 waves (each 64x32), double-buffered LDS, reg-staged.
__launch_bounds__(512, 2)
__global__ void k_gemm(const float* __restrict__ X, const f16* __restrict__ Wall,
                       f16* __restrict__ Pre) {
    __shared__ f16 Al[2][128 * 32];
    __shared__ f16 Bl[2][128 * 32];
    int bid = blockIdx.x;
    int mblk = bid >> 4, nblk = bid & 15;
    int m0 = mblk * 128, n0 = nblk * 128;
    int tid = threadIdx.x;
    int lane = tid & 63, w = tid >> 6;
    int wm = w >> 2, wn = w & 3;              // wave quadrant: 64m x 32n
    int sr = tid >> 2, skq = tid & 3;
    const float* xsrc = X + (size_t)(m0 + sr) * ND + skq * 8;
    const f16*  bsrc = Wall + (size_t)(n0 + (tid >> 2)) * ND + (tid & 3) * 8;

    f32x4 acc[4][2];
#pragma unroll
    for (int a = 0; a < 4; ++a)
#pragma unroll
        for (int b = 0; b < 2; ++b) acc[a][b] = (f32x4){0.f, 0.f, 0.f, 0.f};

    {
        float4 v0 = *(const float4*)(xsrc);
        float4 v1 = *(const float4*)(xsrc + 4);
        f16x8 bv = *(const f16x8*)(bsrc);
        f16x8 h8;
        h8[0] = (f16)v0.x; h8[1] = (f16)v0.y; h8[2] = (f16)v0.z; h8[3] = (f16)v0.w;
        h8[4] = (f16)v1.x; h8[5] = (f16)v1.y; h8[6] = (f16)v1.z; h8[7] = (f16)v1.w;
        *(f16x8*)&Al[0][sr * 32 + skq * 8] = h8;
        *(f16x8*)&Bl[0][tid * 8] = bv;
        __syncthreads();
    }

    for (int kk = 0; kk < 16; ++kk) {
        int buf = kk & 1;
        float4 v0, v1; f16x8 bv;
        bool more = (kk < 15);
        if (more) {
            v0 = *(const float4*)(xsrc + (kk + 1) * 32);
            v1 = *(const float4*)(xsrc + (kk + 1) * 32 + 4);
            bv = *(const f16x8*)(bsrc + (kk + 1) * 32);
        }
        f16x8 af[4], bf[2];
#pragma unroll
        for (int mt = 0; mt < 4; ++mt)
            af[mt] = *(const f16x8*)&Al[buf][(wm * 64 + mt * 16 + (lane & 15)) * 32 + (lane >> 4) * 8];
#pragma unroll
        for (int nt = 0; nt < 2; ++nt)
            bf[nt] = *(const f16x8*)&Bl[buf][(wn * 32 + nt * 16 + (lane & 15)) * 32 + (lane >> 4) * 8];
#pragma unroll
        for (int mt = 0; mt < 4; ++mt)
#pragma unroll
            for (int nt = 0; nt < 2; ++nt)
                acc[mt][nt] = __builtin_amdgcn_mfma_f32_16x16x32_f16(af[mt], bf[nt], acc[mt][nt], 0, 0, 0);
        if (more) {
            f16x8 h8;
            h8[0] = (f16)v0.x; h8[1] = (f16)v0.y; h8[2] = (f16)v0.z; h8[3] = (f16)v0.w;
            h8[4] = (f16)v1.x; h8[5] = (f16)v1.y; h8[6] = (f16)v1.z; h8[7] = (f16)v1.w;
            *(f16x8*)&Al[buf ^ 1][sr * 32 + skq * 8] = h8;
            *(f16x8*)&Bl[buf ^ 1][tid * 8] = bv;
        }
        __syncthreads();
    }

    int col = lane & 15, rg = lane >> 4;
#pragma unroll
    for (int mt = 0; mt < 4; ++mt)
#pragma unroll
        for (int nt = 0; nt < 2; ++nt)
#pragma unroll
            for (int q = 0; q < 4; ++q) {
                int m = m0 + wm * 64 + mt * 16 + rg * 4 + q;
                int n = n0 + wn * 32 + nt * 16 + col;
                Pre[(size_t)m * 2048 + n] = (f16)acc[mt][nt][q];
            }
}

// ---------------------------------------------------------------------------
// Persistent recurrent kernel: 64 WGs, one (batch, dir) each, 512 threads.
// Parity mapping: u = j>>1, p = j&1. p=0 owns gate rows (u, 512+u) = (i,g);
// p=1 owns (256+u, 768+u) = (f,o). Whh fp16: k<192 in 192 VGPRs/thread,
// k in [192,256) in 128 KiB LDS (uint4 per row). h broadcast via LDS (fp16,
// double-buffered). One barrier per step; (i,g)->(f,o) exchange by shfl_xor.
__launch_bounds__(512, 1)
__global__ void k_recur(const f16* __restrict__ Pre, const f16x2* __restrict__ wp,
                        const uint4* __restrict__ wldsg, const float* __restrict__ bsum,
                        const int* __restrict__ lengths, const f16* __restrict__ zslot,
                        float* __restrict__ out) {
    extern __shared__ char smem[];            // [0,131072) wlds | hbuf[2][256] f16
    f16* hbuf = (f16*)(smem + 131072);

    int bid = blockIdx.x;
    int b = bid >> 1, dir = bid & 1;
    int j = threadIdx.x;
    int u = j >> 1, p = j & 1;
    int rowA = p ? 256 + u : u;               // i-gate / f-gate row
    int rowB = rowA + 512;                    // g-gate / o-gate row
    int L = lengths[b];

    // stage LDS weight image (128 KiB), coalesced
    {
        const uint4* src = wldsg + (size_t)dir * 8192;
#pragma unroll
        for (int s = 0; s < 16; ++s) {
            int q = s * 512 + j;
            *(uint4*)(smem + (size_t)q * 16) = src[q];
        }
    }
    // register weights: wreg[r*96 + pair], k < 192
    f16x2 wreg[192];
    {
        const f16x2* wpp = wp + (size_t)(dir * 192) * 512 + j;
#pragma unroll
        for (int e = 0; e < 192; ++e) wreg[e] = wpp[(size_t)e * 512];
    }
    float bs0 = bsum[dir * 1024 + rowA];
    float bs1 = bsum[dir * 1024 + rowB];
    if (j < 64) *(uint4*)(hbuf + j * 8) = (uint4){0u, 0u, 0u, 0u};  // both h bufs
    __syncthreads();

    float cst = 0.0f;
    const size_t baseRow = (size_t)b * NT;
    const int colA = dir * 1024 + rowA;
    const int colB = dir * 1024 + rowB;

    // prefetch pre-activations for t=0
    f16 pn0, pn1;
    {
        int rt = dir ? (L - 1) : 0;
        const f16* q0 = Pre + (baseRow + rt) * 2048;
        pn0 = q0[colA]; pn1 = q0[colB];
    }

    for (int t = 0; t < NT; ++t) {
        float pre0 = (float)pn0, pre1 = (float)pn1;
        // issue prefetch for t+1 (latency hidden under the dot phase)
        {
            int tn = t + 1;
            int rt = dir ? (L - 1 - tn) : tn;
            const f16 *q0, *q1;
            if (tn < NT && rt >= 0) {
                const f16* base = Pre + (baseRow + rt) * 2048;
                q0 = base + colA; q1 = base + colB;
            } else {
                q0 = zslot; q1 = zslot;
            }
            pn0 = *q0; pn1 = *q1;
        }

        const f16* hcur = hbuf + (t & 1) * 256;
        float a0 = bs0 + pre0, a1 = 0.0f;     // rowA accumulators (split for ILP)
        float b0 = bs1 + pre1, b1 = 0.0f;     // rowB accumulators
#pragma unroll
        for (int c = 0; c < 32; ++c) {
            f16x8 hv = *(const f16x8*)(hcur + c * 8);   // broadcast read
            f16x2 h2q[4];
            h2q[0][0] = hv[0]; h2q[0][1] = hv[1];
            h2q[1][0] = hv[2]; h2q[1][1] = hv[3];
            h2q[2][0] = hv[4]; h2q[2][1] = hv[5];
            h2q[3][0] = hv[6]; h2q[3][1] = hv[7];
            f16x2 w0q[4], w1q[4];
            if (c < 24) {
                w0q[0] = wreg[c * 4 + 0]; w0q[1] = wreg[c * 4 + 1];
                w0q[2] = wreg[c * 4 + 2]; w0q[3] = wreg[c * 4 + 3];
                w1q[0] = wreg[96 + c * 4 + 0]; w1q[1] = wreg[96 + c * 4 + 1];
                w1q[2] = wreg[96 + c * 4 + 2]; w1q[3] = wreg[96 + c * 4 + 3];
            } else {
                int cc = c - 24;
                uint4 uA = *(const uint4*)(smem + ((size_t)(cc * 1024) + rowA) * 16);
                uint4 uB = *(const uint4*)(smem + ((size_t)(cc * 1024) + rowB) * 16);
                w0q[0] = __builtin_bit_cast(f16x2, uA.x); w0q[1] = __builtin_bit_cast(f16x2, uA.y);
                w0q[2] = __builtin_bit_cast(f16x2, uA.z); w0q[3] = __builtin_bit_cast(f16x2, uA.w);
                w1q[0] = __builtin_bit_cast(f16x2, uB.x); w1q[1] = __builtin_bit_cast(f16x2, uB.y);
                w1q[2] = __builtin_bit_cast(f16x2, uB.z); w1q[3] = __builtin_bit_cast(f16x2, uB.w);
            }
            a0 = FDOT2(h2q[0], w0q[0], a0);
            b0 = FDOT2(h2q[0], w1q[0], b0);
            a1 = FDOT2(h2q[1], w0q[1], a1);
            b1 = FDOT2(h2q[1], w1q[1], b1);
            a0 = FDOT2(h2q[2], w0q[2], a0);
            b0 = FDOT2(h2q[2], w1q[2], b0);
            a1 = FDOT2(h2q[3], w0q[3], a1);
            b1 = FDOT2(h2q[3], w1q[3], b1);
        }
        float z0 = a0 + a1;                   // p=0: i | p=1: f
        float z1 = b0 + b1;                   // p=0: g | p=1: o

        float a = sigm_f(z0) * tanh_f(z1);    // p=0: sig(i)*tanh(g) (p=1: unused)
        float ap = __shfl_xor(a, 1);          // partner's value, in-wave
        if (p) {
            cst = sigm_f(z0) * cst + ap;      // sig(f)*c + sig(i)*tanh(g)
            float h = sigm_f(z1) * tanh_f(cst);
            out[(baseRow + t) * 512 + dir * 256 + u] = h;
            hbuf[((t + 1) & 1) * 256 + u] = (f16)h;
        }
        __syncthreads();
    }
}

// ---------------------------------------------------------------------------
extern "C" void kernel_launch(void* const* d_in, const int* in_sizes, int n_in,
                              void* d_out, int out_size, void* d_ws, size_t ws_size,
                              hipStream_t stream) {
    (void)in_sizes; (void)n_in; (void)out_size; (void)ws_size;
    const float* x     = (const float*)d_in[0];
    const float* Wf_ih = (const float*)d_in[1];
    const float* Wf_hh = (const float*)d_in[2];
    const float* bf_ih = (const float*)d_in[3];
    const float* bf_hh = (const float*)d_in[4];
    const float* Wb_ih = (const float*)d_in[5];
    const float* Wb_hh = (const float*)d_in[6];
    const float* bb_ih = (const float*)d_in[7];
    const float* bb_hh = (const float*)d_in[8];
    float* out = (float*)d_out;

    char* ws = (char*)d_ws;
    f16*          Pre    = (f16*)(ws + OFF_PRE);
    f16*          Wall   = (f16*)(ws + OFF_WALL);
    f16x2*        wp     = (f16x2*)(ws + OFF_WP);
    uint4*        wldsg  = (uint4*)(ws + OFF_WLDS);
    float*        bsum   = (float*)(ws + OFF_BSUM);
    int*          flags  = (int*)(ws + OFF_FLAGS);
    int*          lens   = (int*)(ws + OFF_LEN);
    unsigned int* zslot  = (unsigned int*)(ws + OFF_Z);

    // 129 KiB dynamic LDS on the recurrent kernel (weights + double h buffer)
    static const size_t RECUR_LDS = 131072 + 1024;
    hipFuncSetAttribute((const void*)k_recur,
                        hipFuncAttributeMaxDynamicSharedMemorySize, (int)RECUR_LDS);

    k_flags <<<MTOT, 256, 0, stream>>>(x, flags);
    k_lenred<<<NB, 256, 0, stream>>>(flags, lens);
    k_wall  <<<1024, 256, 0, stream>>>(Wf_ih, Wb_ih, Wall);
    k_repack<<<421, 512, 0, stream>>>(Wf_hh, Wb_hh, bf_ih, bf_hh, bb_ih, bb_hh,
                                      wp, wldsg, bsum, zslot);
    k_gemm  <<<(MTOT / 128) * (2048 / 128), 512, 0, stream>>>(x, Wall, Pre);
    k_recur <<<NB * 2, 512, RECUR_LDS, stream>>>(Pre, wp, wldsg, bsum, lens,
                                                 (const f16*)zslot, out);
}